// Round 4
// baseline (497.626 us; speedup 1.0000x reference)
//
#include <hip/hip_runtime.h>

// B=8, C=12, Ny=Nx=512, 3x3 depthwise conv SAME pad=1, channel-reduced, + Rq + Dq.
// This version: one wave = one full output row of ONE plane (re or im).
// 8192 waves total = 100% of MI355X wave slots; VGPR capped at 64 via launch_bounds.
#define NY 512
#define NX 512
#define CC 12

__device__ __forceinline__ void row_conv(const float4& v0, const float4& v1,
                                         float w0, float w1, float w2, int lane,
                                         float4& a0, float4& a1)
{
    float l0 = __shfl_up(v1.w, 1);    // px 8i-1 from lane i-1
    if (lane == 0) l0 = 0.f;          // image left edge
    float r1 = __shfl_down(v0.x, 1);  // px 8i+8 from lane i+1
    if (lane == 63) r1 = 0.f;         // image right edge

    a0.x += w0*l0   + w1*v0.x + w2*v0.y;
    a0.y += w0*v0.x + w1*v0.y + w2*v0.z;
    a0.z += w0*v0.y + w1*v0.z + w2*v0.w;
    a0.w += w0*v0.z + w1*v0.w + w2*v1.x;
    a1.x += w0*v0.w + w1*v1.x + w2*v1.y;
    a1.y += w0*v1.x + w1*v1.y + w2*v1.z;
    a1.z += w0*v1.y + w1*v1.z + w2*v1.w;
    a1.w += w0*v1.z + w1*v1.w + w2*r1;
}

// Block: 256 threads = 4 waves, each owning one row. Grid (NY/4, 2 planes, B).
__global__ __launch_bounds__(256, 8)
void momentum_kernel(const float* __restrict__ Rq_re, const float* __restrict__ Rq_im,
                     const float* __restrict__ Dq_re, const float* __restrict__ Dq_im,
                     const float* __restrict__ cache_re, const float* __restrict__ cache_im,
                     const float* __restrict__ filt, float* __restrict__ out)
{
    const int tid  = threadIdx.x;
    const int wave = tid >> 6;
    const int lane = tid & 63;
    const int y    = blockIdx.x * 4 + wave;
    const int p    = blockIdx.y;             // 0 = re, 1 = im
    const int b    = blockIdx.z;

    const float* Rq    = p ? Rq_im    : Rq_re;
    const float* Dq    = p ? Dq_im    : Dq_re;
    const float* cache = p ? cache_im : cache_re;

    const int x0 = lane * 8;

    // y-halo: clamped row + 0/1 weight mask (wave-uniform, branch-free loads)
    const int   ym1   = (y > 0)      ? y - 1 : 0;
    const int   yp1   = (y < NY - 1) ? y + 1 : NY - 1;
    const float m_top = (y > 0)      ? 1.f : 0.f;
    const float m_bot = (y < NY - 1) ? 1.f : 0.f;

    const int off_t = ym1 * NX + x0;
    const int off_m = y   * NX + x0;
    const int off_b = yp1 * NX + x0;

    // ---- pointwise: Rq + Dq ----
    float4 a0, a1;
    {
        const int base = (b * NY + y) * NX + x0;
        const float4 q0 = *(const float4*)(Rq + base);
        const float4 q1 = *(const float4*)(Rq + base + 4);
        const float4 d0 = *(const float4*)(Dq + base);
        const float4 d1 = *(const float4*)(Dq + base + 4);
        a0 = make_float4(q0.x + d0.x, q0.y + d0.y, q0.z + d0.z, q0.w + d0.w);
        a1 = make_float4(q1.x + d1.x, q1.y + d1.y, q1.z + d1.z, q1.w + d1.w);
    }

    // ---- channel-reduced depthwise 3x3: 6 unconditional loads per channel ----
    const size_t plane_stride = (size_t)NY * NX;
    const float* cp = cache + (size_t)b * CC * plane_stride;

    #pragma unroll
    for (int c = 0; c < CC; ++c) {
        const float* pl = cp + (size_t)c * plane_stride;
        const float4 t0 = *(const float4*)(pl + off_t);
        const float4 t1 = *(const float4*)(pl + off_t + 4);
        const float4 m0 = *(const float4*)(pl + off_m);
        const float4 m1 = *(const float4*)(pl + off_m + 4);
        const float4 b0 = *(const float4*)(pl + off_b);
        const float4 b1 = *(const float4*)(pl + off_b + 4);

        const float* f = filt + c * 9;        // uniform -> s_load path
        const float w00 = f[0] * m_top, w01 = f[1] * m_top, w02 = f[2] * m_top;
        const float w10 = f[3],         w11 = f[4],         w12 = f[5];
        const float w20 = f[6] * m_bot, w21 = f[7] * m_bot, w22 = f[8] * m_bot;

        row_conv(t0, t1, w00, w01, w02, lane, a0, a1);
        row_conv(m0, m1, w10, w11, w12, lane, a0, a1);
        row_conv(b0, b1, w20, w21, w22, lane, a0, a1);
    }

    // ---- store (B, 2, NY, NX) ----
    float* o = out + ((size_t)(b * 2 + p) * NY + y) * NX + x0;
    *(float4*)(o)     = a0;
    *(float4*)(o + 4) = a1;
}

extern "C" void kernel_launch(void* const* d_in, const int* in_sizes, int n_in,
                              void* d_out, int out_size, void* d_ws, size_t ws_size,
                              hipStream_t stream) {
    const float* Rq_re    = (const float*)d_in[0];
    const float* Rq_im    = (const float*)d_in[1];
    const float* Dq_re    = (const float*)d_in[2];
    const float* Dq_im    = (const float*)d_in[3];
    const float* cache_re = (const float*)d_in[4];
    const float* cache_im = (const float*)d_in[5];
    const float* filt     = (const float*)d_in[6];
    float* out = (float*)d_out;

    const int B = in_sizes[0] / (NY * NX);   // = 8

    dim3 block(256);
    dim3 grid(NY / 4, 2, B);
    momentum_kernel<<<grid, block, 0, stream>>>(Rq_re, Rq_im, Dq_re, Dq_im,
                                                cache_re, cache_im, filt, out);
}

// Round 5
// 408.018 us; speedup vs baseline: 1.2196x; 1.2196x over previous
//
#include <hip/hip_runtime.h>

// B=8, C=12, Ny=Nx=512, 3x3 depthwise conv SAME pad=1, channel-reduced, + Rq + Dq.
// Round-3 structure (1 wave = 1 full output row, re+im fused) + explicit
// software pipelining: one 6-load plane batch always in flight while the
// previous batch is convolved. All buffer indices static (ping-pong macros).
#define NY 512
#define NX 512
#define CC 12

__device__ __forceinline__ void row_conv(const float4& v0, const float4& v1,
                                         float w0, float w1, float w2, int lane,
                                         float4& a0, float4& a1)
{
    float l0 = __shfl_up(v1.w, 1);    // px 8i-1 from lane i-1
    if (lane == 0) l0 = 0.f;          // image left edge
    float r1 = __shfl_down(v0.x, 1);  // px 8i+8 from lane i+1
    if (lane == 63) r1 = 0.f;         // image right edge

    a0.x += w0*l0   + w1*v0.x + w2*v0.y;
    a0.y += w0*v0.x + w1*v0.y + w2*v0.z;
    a0.z += w0*v0.y + w1*v0.z + w2*v0.w;
    a0.w += w0*v0.z + w1*v0.w + w2*v1.x;
    a1.x += w0*v0.w + w1*v1.x + w2*v1.y;
    a1.y += w0*v1.x + w1*v1.y + w2*v1.z;
    a1.z += w0*v1.y + w1*v1.z + w2*v1.w;
    a1.w += w0*v1.z + w1*v1.w + w2*r1;
}

// 6 vector loads of one plane's 3 rows into named regs (assignment, not decl)
#define LOAD6(P, base)                              \
    P##t0 = *(const float4*)((base) + off_t);       \
    P##t1 = *(const float4*)((base) + off_t + 4);   \
    P##m0 = *(const float4*)((base) + off_m);       \
    P##m1 = *(const float4*)((base) + off_m + 4);   \
    P##b0 = *(const float4*)((base) + off_b);       \
    P##b1 = *(const float4*)((base) + off_b + 4);

#define CONV6(P, A0, A1)                                     \
    row_conv(P##t0, P##t1, w00, w01, w02, lane, A0, A1);     \
    row_conv(P##m0, P##m1, w10, w11, w12, lane, A0, A1);     \
    row_conv(P##b0, P##b1, w20, w21, w22, lane, A0, A1);

// One channel: issue im(c) + re(c+1) loads, then convolve re(c) (already
// resident, no wait) and im(c) (waits only its own 6 loads).
#define CHANNEL_STEP(C, CUR, NXT)                                         \
    {                                                                     \
        const float* pim_ = ci_base + (size_t)(C) * PS;                   \
        LOAD6(i, pim_)                                                    \
        if ((C) + 1 < CC) {                                               \
            const float* pre_ = cr_base + (size_t)((C) + 1) * PS;         \
            LOAD6(NXT, pre_)                                              \
        }                                                                 \
        const float* f_ = filt + (C) * 9;                                 \
        const float w00 = f_[0] * m_top, w01 = f_[1] * m_top,             \
                    w02 = f_[2] * m_top;                                  \
        const float w10 = f_[3], w11 = f_[4], w12 = f_[5];                \
        const float w20 = f_[6] * m_bot, w21 = f_[7] * m_bot,             \
                    w22 = f_[8] * m_bot;                                  \
        CONV6(CUR, ar0, ar1)                                              \
        CONV6(i, ai0, ai1)                                                \
    }

// Block: 256 threads = 4 waves, each owning one full row (re+im).
// Grid (NY/4, B) = (128, 8). VGPR cap 128 via min 4 waves/EU.
__global__ __launch_bounds__(256, 4)
void momentum_kernel(const float* __restrict__ Rq_re, const float* __restrict__ Rq_im,
                     const float* __restrict__ Dq_re, const float* __restrict__ Dq_im,
                     const float* __restrict__ cache_re, const float* __restrict__ cache_im,
                     const float* __restrict__ filt, float* __restrict__ out)
{
    const int tid  = threadIdx.x;
    const int wave = tid >> 6;
    const int lane = tid & 63;
    const int y    = blockIdx.x * 4 + wave;
    const int b    = blockIdx.y;
    const int x0   = lane * 8;

    // y-halo: clamped row + 0/1 weight mask (wave-uniform, branch-free loads)
    const int   ym1   = (y > 0)      ? y - 1 : 0;
    const int   yp1   = (y < NY - 1) ? y + 1 : NY - 1;
    const float m_top = (y > 0)      ? 1.f : 0.f;
    const float m_bot = (y < NY - 1) ? 1.f : 0.f;

    const int off_t = ym1 * NX + x0;
    const int off_m = y   * NX + x0;
    const int off_b = yp1 * NX + x0;

    const size_t PS = (size_t)NY * NX;
    const float* cr_base = cache_re + (size_t)b * CC * PS;
    const float* ci_base = cache_im + (size_t)b * CC * PS;

    // ---- pointwise: Rq + Dq (8 independent loads, one batch) ----
    float4 ar0, ar1, ai0, ai1;
    {
        const int base = (b * NY + y) * NX + x0;
        const float4 q0 = *(const float4*)(Rq_re + base);
        const float4 q1 = *(const float4*)(Rq_re + base + 4);
        const float4 d0 = *(const float4*)(Dq_re + base);
        const float4 d1 = *(const float4*)(Dq_re + base + 4);
        const float4 u0 = *(const float4*)(Rq_im + base);
        const float4 u1 = *(const float4*)(Rq_im + base + 4);
        const float4 e0 = *(const float4*)(Dq_im + base);
        const float4 e1 = *(const float4*)(Dq_im + base + 4);
        ar0 = make_float4(q0.x + d0.x, q0.y + d0.y, q0.z + d0.z, q0.w + d0.w);
        ar1 = make_float4(q1.x + d1.x, q1.y + d1.y, q1.z + d1.z, q1.w + d1.w);
        ai0 = make_float4(u0.x + e0.x, u0.y + e0.y, u0.z + e0.z, u0.w + e0.w);
        ai1 = make_float4(u1.x + e1.x, u1.y + e1.y, u1.z + e1.z, u1.w + e1.w);
    }

    // ---- pipelined channel loop: r*/n* ping-pong re-buffers, i* im-buffer ----
    float4 rt0, rt1, rm0, rm1, rb0, rb1;   // re buffer A
    float4 nt0, nt1, nm0, nm1, nb0, nb1;   // re buffer B
    float4 it0, it1, im0, im1, ib0, ib1;   // im buffer

    LOAD6(r, cr_base)                       // prologue: re(0)

    #pragma unroll
    for (int cc = 0; cc < CC; cc += 2) {
        CHANNEL_STEP(cc,     r, n)
        CHANNEL_STEP(cc + 1, n, r)
    }

    // ---- store (B, 2, NY, NX) ----
    float* o_re = out + ((size_t)(b * 2 + 0) * NY + y) * NX + x0;
    float* o_im = out + ((size_t)(b * 2 + 1) * NY + y) * NX + x0;
    *(float4*)(o_re)     = ar0;
    *(float4*)(o_re + 4) = ar1;
    *(float4*)(o_im)     = ai0;
    *(float4*)(o_im + 4) = ai1;
}

extern "C" void kernel_launch(void* const* d_in, const int* in_sizes, int n_in,
                              void* d_out, int out_size, void* d_ws, size_t ws_size,
                              hipStream_t stream) {
    const float* Rq_re    = (const float*)d_in[0];
    const float* Rq_im    = (const float*)d_in[1];
    const float* Dq_re    = (const float*)d_in[2];
    const float* Dq_im    = (const float*)d_in[3];
    const float* cache_re = (const float*)d_in[4];
    const float* cache_im = (const float*)d_in[5];
    const float* filt     = (const float*)d_in[6];
    float* out = (float*)d_out;

    const int B = in_sizes[0] / (NY * NX);   // = 8

    dim3 block(256);
    dim3 grid(NY / 4, B);
    momentum_kernel<<<grid, block, 0, stream>>>(Rq_re, Rq_im, Dq_re, Dq_im,
                                                cache_re, cache_im, filt, out);
}

// Round 6
// 92.520 us; speedup vs baseline: 5.3786x; 4.4101x over previous
//
#include <hip/hip_runtime.h>

// B=8, C=12, Ny=Nx=512, 3x3 depthwise conv SAME pad=1, channel-reduced, + Rq + Dq.
// Round-5 software pipeline, but WITHOUT the VGPR-capping launch_bounds min-waves
// arg: on this toolchain (256,4) caps VGPR at 64 (r3/r5) and (256,8) at 32 (r4),
// which caused scratch spills / serialized loads. (256) alone lets the allocator
// take ~100-130 regs; 4 waves/SIMD still fit at <=128 VGPR.
#define NY 512
#define NX 512
#define CC 12

__device__ __forceinline__ void row_conv(const float4& v0, const float4& v1,
                                         float w0, float w1, float w2, int lane,
                                         float4& a0, float4& a1)
{
    float l0 = __shfl_up(v1.w, 1);    // px 8i-1 from lane i-1
    if (lane == 0) l0 = 0.f;          // image left edge
    float r1 = __shfl_down(v0.x, 1);  // px 8i+8 from lane i+1
    if (lane == 63) r1 = 0.f;         // image right edge

    a0.x += w0*l0   + w1*v0.x + w2*v0.y;
    a0.y += w0*v0.x + w1*v0.y + w2*v0.z;
    a0.z += w0*v0.y + w1*v0.z + w2*v0.w;
    a0.w += w0*v0.z + w1*v0.w + w2*v1.x;
    a1.x += w0*v0.w + w1*v1.x + w2*v1.y;
    a1.y += w0*v1.x + w1*v1.y + w2*v1.z;
    a1.z += w0*v1.y + w1*v1.z + w2*v1.w;
    a1.w += w0*v1.z + w1*v1.w + w2*r1;
}

// 6 vector loads of one plane's 3 rows into named regs (assignment, not decl)
#define LOAD6(P, base)                              \
    P##t0 = *(const float4*)((base) + off_t);       \
    P##t1 = *(const float4*)((base) + off_t + 4);   \
    P##m0 = *(const float4*)((base) + off_m);       \
    P##m1 = *(const float4*)((base) + off_m + 4);   \
    P##b0 = *(const float4*)((base) + off_b);       \
    P##b1 = *(const float4*)((base) + off_b + 4);

#define CONV6(P, A0, A1)                                     \
    row_conv(P##t0, P##t1, w00, w01, w02, lane, A0, A1);     \
    row_conv(P##m0, P##m1, w10, w11, w12, lane, A0, A1);     \
    row_conv(P##b0, P##b1, w20, w21, w22, lane, A0, A1);

// One channel: issue im(c) + re(c+1) loads, then convolve re(c) (already
// resident, no wait) and im(c) (waits only its own 6 loads).
#define CHANNEL_STEP(C, CUR, NXT)                                         \
    {                                                                     \
        const float* pim_ = ci_base + (size_t)(C) * PS;                   \
        LOAD6(i, pim_)                                                    \
        if ((C) + 1 < CC) {                                               \
            const float* pre_ = cr_base + (size_t)((C) + 1) * PS;         \
            LOAD6(NXT, pre_)                                              \
        }                                                                 \
        const float* f_ = filt + (C) * 9;                                 \
        const float w00 = f_[0] * m_top, w01 = f_[1] * m_top,             \
                    w02 = f_[2] * m_top;                                  \
        const float w10 = f_[3], w11 = f_[4], w12 = f_[5];                \
        const float w20 = f_[6] * m_bot, w21 = f_[7] * m_bot,             \
                    w22 = f_[8] * m_bot;                                  \
        CONV6(CUR, ar0, ar1)                                              \
        CONV6(i, ai0, ai1)                                                \
    }

// Block: 256 threads = 4 waves, each owning one full row (re+im).
// Grid (NY/4, B) = (128, 8) = 1024 blocks -> 4096 waves.
__global__ __launch_bounds__(256)
void momentum_kernel(const float* __restrict__ Rq_re, const float* __restrict__ Rq_im,
                     const float* __restrict__ Dq_re, const float* __restrict__ Dq_im,
                     const float* __restrict__ cache_re, const float* __restrict__ cache_im,
                     const float* __restrict__ filt, float* __restrict__ out)
{
    const int tid  = threadIdx.x;
    const int wave = tid >> 6;
    const int lane = tid & 63;
    const int y    = blockIdx.x * 4 + wave;
    const int b    = blockIdx.y;
    const int x0   = lane * 8;

    // y-halo: clamped row + 0/1 weight mask (wave-uniform, branch-free loads)
    const int   ym1   = (y > 0)      ? y - 1 : 0;
    const int   yp1   = (y < NY - 1) ? y + 1 : NY - 1;
    const float m_top = (y > 0)      ? 1.f : 0.f;
    const float m_bot = (y < NY - 1) ? 1.f : 0.f;

    const int off_t = ym1 * NX + x0;
    const int off_m = y   * NX + x0;
    const int off_b = yp1 * NX + x0;

    const size_t PS = (size_t)NY * NX;
    const float* cr_base = cache_re + (size_t)b * CC * PS;
    const float* ci_base = cache_im + (size_t)b * CC * PS;

    // ---- pointwise: Rq + Dq (8 independent loads, one batch) ----
    float4 ar0, ar1, ai0, ai1;
    {
        const int base = (b * NY + y) * NX + x0;
        const float4 q0 = *(const float4*)(Rq_re + base);
        const float4 q1 = *(const float4*)(Rq_re + base + 4);
        const float4 d0 = *(const float4*)(Dq_re + base);
        const float4 d1 = *(const float4*)(Dq_re + base + 4);
        const float4 u0 = *(const float4*)(Rq_im + base);
        const float4 u1 = *(const float4*)(Rq_im + base + 4);
        const float4 e0 = *(const float4*)(Dq_im + base);
        const float4 e1 = *(const float4*)(Dq_im + base + 4);
        ar0 = make_float4(q0.x + d0.x, q0.y + d0.y, q0.z + d0.z, q0.w + d0.w);
        ar1 = make_float4(q1.x + d1.x, q1.y + d1.y, q1.z + d1.z, q1.w + d1.w);
        ai0 = make_float4(u0.x + e0.x, u0.y + e0.y, u0.z + e0.z, u0.w + e0.w);
        ai1 = make_float4(u1.x + e1.x, u1.y + e1.y, u1.z + e1.z, u1.w + e1.w);
    }

    // ---- pipelined channel loop: r*/n* ping-pong re-buffers, i* im-buffer ----
    float4 rt0, rt1, rm0, rm1, rb0, rb1;   // re buffer A
    float4 nt0, nt1, nm0, nm1, nb0, nb1;   // re buffer B
    float4 it0, it1, im0, im1, ib0, ib1;   // im buffer

    LOAD6(r, cr_base)                       // prologue: re(0)

    #pragma unroll
    for (int cc = 0; cc < CC; cc += 2) {
        CHANNEL_STEP(cc,     r, n)
        CHANNEL_STEP(cc + 1, n, r)
    }

    // ---- store (B, 2, NY, NX) ----
    float* o_re = out + ((size_t)(b * 2 + 0) * NY + y) * NX + x0;
    float* o_im = out + ((size_t)(b * 2 + 1) * NY + y) * NX + x0;
    *(float4*)(o_re)     = ar0;
    *(float4*)(o_re + 4) = ar1;
    *(float4*)(o_im)     = ai0;
    *(float4*)(o_im + 4) = ai1;
}

extern "C" void kernel_launch(void* const* d_in, const int* in_sizes, int n_in,
                              void* d_out, int out_size, void* d_ws, size_t ws_size,
                              hipStream_t stream) {
    const float* Rq_re    = (const float*)d_in[0];
    const float* Rq_im    = (const float*)d_in[1];
    const float* Dq_re    = (const float*)d_in[2];
    const float* Dq_im    = (const float*)d_in[3];
    const float* cache_re = (const float*)d_in[4];
    const float* cache_im = (const float*)d_in[5];
    const float* filt     = (const float*)d_in[6];
    float* out = (float*)d_out;

    const int B = in_sizes[0] / (NY * NX);   // = 8

    dim3 block(256);
    dim3 grid(NY / 4, B);
    momentum_kernel<<<grid, block, 0, stream>>>(Rq_re, Rq_im, Dq_re, Dq_im,
                                                cache_re, cache_im, filt, out);
}